// Round 9
// baseline (330.306 us; speedup 1.0000x reference)
//
#include <hip/hip_runtime.h>

#define Bn 32
#define Sn 4096
#define Dn 64
#define Hn 128
#define CHUNK 128
#define WARM  64
#define NCHUNK (Sn / CHUNK)   // 32 -> 1024 blocks = 4 per CU

typedef unsigned short ushort_t;
typedef unsigned int uint_t;
typedef ushort_t ushort4v __attribute__((ext_vector_type(4)));
typedef ushort_t ushort8v __attribute__((ext_vector_type(8)));
typedef _Float16 half2_t __attribute__((ext_vector_type(2)));
typedef _Float16 half4_t __attribute__((ext_vector_type(4)));
typedef _Float16 half8_t __attribute__((ext_vector_type(8)));
typedef unsigned int uint2v __attribute__((ext_vector_type(2)));

__device__ __forceinline__ float fsig(float x)  { return 1.0f / (1.0f + __expf(-x)); }
__device__ __forceinline__ float ftanh(float x) { return 2.0f / (1.0f + __expf(-2.0f * x)) - 1.0f; }

__device__ __forceinline__ ushort_t f2bf(float f) {
    unsigned int b = __float_as_uint(f);
    b += 0x7fffu + ((b >> 16) & 1u);
    return (ushort_t)(b >> 16);
}
__device__ __forceinline__ float bf2f(ushort_t u) {
    return __uint_as_float(((unsigned int)u) << 16);
}

__device__ __forceinline__ void bar_lgkm() {
    asm volatile("s_waitcnt lgkmcnt(0)" ::: "memory");
    __builtin_amdgcn_s_barrier();
    asm volatile("" ::: "memory");
}

// NQ x half8 window read + NQ*4 fdot2, 4-way acc split, init carries bias/pre.
template<int NQ>
__device__ __forceinline__ float windot(const _Float16* p, const half2_t* w, float init) {
    float a0 = init, a1 = 0.f, a2 = 0.f, a3 = 0.f;
    const half8_t* cb = (const half8_t*)p;
    #pragma unroll
    for (int q = 0; q < NQ; ++q) {
        half8_t v = cb[q];
        a0 = __builtin_amdgcn_fdot2(w[4 * q + 0], (half2_t){v[0], v[1]}, a0, false);
        a1 = __builtin_amdgcn_fdot2(w[4 * q + 1], (half2_t){v[2], v[3]}, a1, false);
        a2 = __builtin_amdgcn_fdot2(w[4 * q + 2], (half2_t){v[4], v[5]}, a2, false);
        a3 = __builtin_amdgcn_fdot2(w[4 * q + 3], (half2_t){v[6], v[7]}, a3, false);
    }
    return (a0 + a1) + (a2 + a3);
}

// ===========================================================================
// ============================ NEW (precomp) PATH ===========================
// ===========================================================================

// ---------------------------------------------------------------------------
// pre_k: pre-activation GEMM over x. For units j<64 (groups 0,1 — the only
// ones whose windows touch x): pre[row][gate][j] = sum_c Wg[j,cl,2]*x[c] + bias.
// Output packed: pzh[row][j] = half2(pre_z, pre_h) as uint; prr[row][j] = half.
// Grid: 1024 blocks x 256 thr; block = 128 rows. Two o-passes, acc[8][6].
// o = j*3 + gate  (gate 0=z, 1=r, 2=h).
// ---------------------------------------------------------------------------
__global__ __launch_bounds__(256) void pre_k(
    const float* __restrict__ x,
    const float* __restrict__ Wz, const float* __restrict__ bz,
    const float* __restrict__ Wr, const float* __restrict__ br,
    const float* __restrict__ Wh, const float* __restrict__ bh,
    uint_t* __restrict__ pzh, ushort_t* __restrict__ prr)
{
    __shared__ __align__(16) _Float16 xt[128 * 72];    // [r][c] pad 72
    __shared__ __align__(16) _Float16 wfT[192 * 72];   // [o][c] pad 72

    const int tid = threadIdx.x;
    const int row0 = blockIdx.x * 128;

    // stage x tile (fp32 -> fp16)
    #pragma unroll
    for (int it = 0; it < 8; ++it) {
        const int idx = it * 1024 + tid * 4;
        const int r = idx >> 6, c = idx & 63;
        float4 v = *(const float4*)(x + (size_t)row0 * 64 + idx);
        half4_t hv = {(_Float16)v.x, (_Float16)v.y, (_Float16)v.z, (_Float16)v.w};
        *(half4_t*)(&xt[r * 72 + c]) = hv;
    }
    // stage fused x-part weight matrix wfT[o][c]
    if (tid < 192) {
        const int o = tid, j = o / 3, gate = o % 3;
        const float* Wg = (gate == 0) ? Wz : (gate == 1) ? Wr : Wh;
        for (int c = 0; c < 64; ++c) {
            float v = 0.f;
            if (j < 32) { if (c < 48) v = Wg[j * 240 + 5 * c + 2]; }
            else        { if (c >= 48) v = Wg[j * 240 + 5 * (c - 48) + 2]; }
            wfT[o * 72 + c] = (_Float16)v;
        }
    }
    __syncthreads();

    const int tx = tid & 15, ty = tid >> 4;

    #pragma unroll
    for (int pass = 0; pass < 2; ++pass) {
        const int o0 = pass * 96 + tx * 6;
        float acc[8][6];
        #pragma unroll
        for (int o1 = 0; o1 < 6; ++o1) {
            const int o = o0 + o1, j = o / 3, gate = o % 3;
            const float bias = (gate == 0) ? bz[j] : (gate == 1) ? br[j] : bh[j];
            #pragma unroll
            for (int i = 0; i < 8; ++i) acc[i][o1] = bias;
        }
        for (int c8 = 0; c8 < 8; ++c8) {
            const int kl = c8 * 8;
            half8_t xv[8], wv[6];
            #pragma unroll
            for (int i = 0; i < 8; ++i)
                xv[i] = *(const half8_t*)(&xt[(ty + 16 * i) * 72 + kl]);
            #pragma unroll
            for (int o1 = 0; o1 < 6; ++o1)
                wv[o1] = *(const half8_t*)(&wfT[(o0 + o1) * 72 + kl]);
            #pragma unroll
            for (int o1 = 0; o1 < 6; ++o1)
                #pragma unroll
                for (int i = 0; i < 8; ++i) {
                    acc[i][o1] = __builtin_amdgcn_fdot2((half2_t){xv[i][0], xv[i][1]},
                                  (half2_t){wv[o1][0], wv[o1][1]}, acc[i][o1], false);
                    acc[i][o1] = __builtin_amdgcn_fdot2((half2_t){xv[i][2], xv[i][3]},
                                  (half2_t){wv[o1][2], wv[o1][3]}, acc[i][o1], false);
                    acc[i][o1] = __builtin_amdgcn_fdot2((half2_t){xv[i][4], xv[i][5]},
                                  (half2_t){wv[o1][4], wv[o1][5]}, acc[i][o1], false);
                    acc[i][o1] = __builtin_amdgcn_fdot2((half2_t){xv[i][6], xv[i][7]},
                                  (half2_t){wv[o1][6], wv[o1][7]}, acc[i][o1], false);
                }
        }
        const int u0 = o0 / 3;   // 2 units per thread per pass
        #pragma unroll
        for (int i = 0; i < 8; ++i) {
            const size_t row = row0 + ty + 16 * i;
            uint_t pz0 = __builtin_bit_cast(uint_t,
                (half2_t){(_Float16)acc[i][0], (_Float16)acc[i][2]});
            uint_t pz1 = __builtin_bit_cast(uint_t,
                (half2_t){(_Float16)acc[i][3], (_Float16)acc[i][5]});
            uint2v pp = {pz0, pz1};
            *(uint2v*)(&pzh[row * 64 + u0]) = pp;
            half2_t pr = {(_Float16)acc[i][1], (_Float16)acc[i][4]};
            *(uint_t*)(&prr[row * 64 + u0]) = __builtin_bit_cast(uint_t, pr);
        }
    }
}

// ---------------------------------------------------------------------------
// gru_rec_p: slim recurrence. All x-dependence precomputed.
// comb = h (128 fp16), comb2 = r*h (128 fp16). 2 lgkm barriers/step.
// Wave roles: k<128 = z (+h_hat, update); k>=128 = r (+g-store of t-1).
// Window: j<64 -> comb[0:32) (4 reads, 16 dot2; zero weights for j<32);
//         j>=64 -> comb[hb..hb+48) (6 reads, 24 dot2), hb = 32 or 80.
// ---------------------------------------------------------------------------
__global__ __launch_bounds__(256, 4) void gru_rec_p(
    const uint_t* __restrict__ pzh, const ushort_t* __restrict__ prr,
    const float* __restrict__ Wz, const float* __restrict__ bz,
    const float* __restrict__ Wr, const float* __restrict__ br,
    const float* __restrict__ Wh, const float* __restrict__ bh,
    ushort_t* __restrict__ gout)
{
    __shared__ __align__(16) _Float16 comb[128];
    __shared__ __align__(16) _Float16 comb2[128];

    const int b  = blockIdx.x & 31;
    const int p  = blockIdx.x >> 5;
    const int tw = p * CHUNK;
    const int t0 = (p == 0) ? 0 : tw - WARM;
    const int t1 = tw + CHUNK;

    const int k = threadIdx.x;
    const int j = k & 127;
    const bool zlane = (k < 128);
    const bool lowj = (j < 64);
    const int hb = (j >= 96) ? 80 : 32;           // h-window base for j>=64

    // h-part weights (gate + h_hat for z-lanes; gate only for r-lanes)
    half2_t wg[24], whh[24];
    {
        const float* Wg = zlane ? Wz : Wr;
        if (j >= 64) {
            #pragma unroll
            for (int c = 0; c < 24; ++c) {
                wg[c]  = (half2_t){(_Float16)Wg[j * 240 + 10 * c + 2],
                                   (_Float16)Wg[j * 240 + 10 * c + 7]};
                whh[c] = (half2_t){(_Float16)Wh[j * 240 + 10 * c + 2],
                                   (_Float16)Wh[j * 240 + 10 * c + 7]};
            }
        } else if (j >= 32) {
            #pragma unroll
            for (int c = 0; c < 16; ++c) {
                wg[c]  = (half2_t){(_Float16)Wg[j * 240 + 10 * c + 82],
                                   (_Float16)Wg[j * 240 + 10 * c + 87]};
                whh[c] = (half2_t){(_Float16)Wh[j * 240 + 10 * c + 82],
                                   (_Float16)Wh[j * 240 + 10 * c + 87]};
            }
        } else {
            #pragma unroll
            for (int c = 0; c < 16; ++c) {
                wg[c] = (half2_t){(_Float16)0.f, (_Float16)0.f};
                whh[c] = (half2_t){(_Float16)0.f, (_Float16)0.f};
            }
        }
    }
    // biases for j>=64 (j<64 biases folded into precomp)
    const float bg_hi = lowj ? 0.f : (zlane ? bz[j] : br[j]);
    const float bh_hi = lowj ? 0.f : bh[j];

    const uint_t*   pzb = pzh + (size_t)b * Sn * 64;
    const ushort_t* prb = prr + (size_t)b * Sn * 64;
    ushort_t* gb = gout + (size_t)b * Sn * Hn;

    comb[j] = (_Float16)0.f;    // h0 = 0 (both halves write same value)

    uint_t  pz_next = 0; ushort_t pr_next = 0;
    if (zlane && lowj)  pz_next = pzb[(size_t)t0 * 64 + j];
    if (!zlane && lowj) pr_next = prb[(size_t)t0 * 64 + j];
    bar_lgkm();

    float z = 0.f, hreg = 0.f;
    half2_t pzv = (half2_t){(_Float16)0.f, (_Float16)0.f};

    for (int t = t0; t < t1; ++t) {
        // ---------------- phase A: gates ----------------
        const int tn = (t + 1 < Sn) ? (t + 1) : (Sn - 1);
        float preG;
        if (zlane) {
            pzv = __builtin_bit_cast(half2_t, pz_next);
            if (lowj) pz_next = pzb[(size_t)tn * 64 + j];
            preG = lowj ? (float)pzv[0] : bg_hi;
        } else {
            float prf = (float)__builtin_bit_cast(_Float16, pr_next);
            if (lowj) pr_next = prb[(size_t)tn * 64 + j];
            preG = lowj ? prf : bg_hi;
        }
        float hd = lowj ? windot<4>(comb, wg, preG)
                        : windot<6>(comb + hb, wg, preG);
        const float gate = fsig(hd);
        if (zlane) {
            z = gate;
        } else {
            const _Float16 hj16 = comb[j];
            comb2[j] = (_Float16)(gate * (float)hj16);         // r*h
            if (t > tw)                                         // g-store t-1
                gb[(size_t)(t - 1) * Hn + j] = __builtin_bit_cast(ushort_t, hj16);
        }
        bar_lgkm();

        // ---------------- phase B: h_hat + update (z-waves only) ----------------
        if (zlane) {
            const float preH = lowj ? (float)pzv[1] : bh_hi;
            float hdh = lowj ? windot<4>(comb2, whh, preH)
                             : windot<6>(comb2 + hb, whh, preH);
            const float hh = ftanh(hdh);
            hreg = hreg + z * (hh - hreg);
            comb[j] = (_Float16)hreg;
        }
        bar_lgkm();
    }
    if (zlane) {
        _Float16 hv = (_Float16)hreg;
        gb[(size_t)(t1 - 1) * Hn + j] = __builtin_bit_cast(ushort_t, hv);
    }
}

// ---------------------------------------------------------------------------
// score_tile_h: scores = tanh(g . W1 + b1) . W2 + b2, g in fp16, fdot2 core.
// ---------------------------------------------------------------------------
__global__ __launch_bounds__(256, 2) void score_tile_h(
    const ushort_t* __restrict__ g, const float* __restrict__ W1,
    const float* __restrict__ b1, const float* __restrict__ W2,
    const float* __restrict__ b2, float* __restrict__ scores)
{
    __shared__ __align__(16) _Float16 gph[128 * 136];   // [r][k]
    __shared__ __align__(16) _Float16 w1p[128 * 136];   // [k][j]

    const int tid = threadIdx.x;
    const int row0 = blockIdx.x * 128;
    const int tx = tid & 15, ty = tid >> 4;
    const int j0 = tx * 8;

    #pragma unroll
    for (int it = 0; it < 8; ++it) {           // g tile: fp16 direct copy
        const int idx = it * 2048 + tid * 8;
        const int rr = idx >> 7, cc = idx & 127;
        half8_t v = *(const half8_t*)(g + (size_t)row0 * 128 + idx);
        *(half8_t*)(&gph[rr * 136 + cc]) = v;
    }
    #pragma unroll
    for (int it = 0; it < 16; ++it) {          // W1: fp32 -> fp16
        const int idx = it * 1024 + tid * 4;
        const int rr = idx >> 7, cc = idx & 127;
        float4 u = *(const float4*)(W1 + idx);
        half4_t hv = {(_Float16)u.x, (_Float16)u.y, (_Float16)u.z, (_Float16)u.w};
        *(half4_t*)(&w1p[rr * 136 + cc]) = hv;
    }

    float b1r[8], w2r[8];
    #pragma unroll
    for (int i = 0; i < 8; ++i) { b1r[i] = b1[j0 + i]; w2r[i] = W2[j0 + i]; }
    const float b2s = b2[0];
    __syncthreads();

    float y[8][8];
    #pragma unroll
    for (int i = 0; i < 8; ++i)
        #pragma unroll
        for (int jj = 0; jj < 8; ++jj) y[i][jj] = b1r[jj];

    for (int k8 = 0; k8 < 16; ++k8) {
        const int kl = k8 * 8;
        half8_t gf[8], wfk[8];
        #pragma unroll
        for (int i = 0; i < 8; ++i)
            gf[i] = *(const half8_t*)(&gph[(ty + 16 * i) * 136 + kl]);
        #pragma unroll
        for (int kk = 0; kk < 8; ++kk)
            wfk[kk] = *(const half8_t*)(&w1p[(kl + kk) * 136 + j0]);
        #pragma unroll
        for (int m = 0; m < 4; ++m) {
            half2_t wp[8];
            #pragma unroll
            for (int jj = 0; jj < 8; ++jj)
                wp[jj] = (half2_t){wfk[2 * m][jj], wfk[2 * m + 1][jj]};
            #pragma unroll
            for (int i = 0; i < 8; ++i) {
                half2_t gp = (half2_t){gf[i][2 * m], gf[i][2 * m + 1]};
                #pragma unroll
                for (int jj = 0; jj < 8; ++jj)
                    y[i][jj] = __builtin_amdgcn_fdot2(gp, wp[jj], y[i][jj], false);
            }
        }
    }

    #pragma unroll
    for (int i = 0; i < 8; ++i) {
        float s = 0.f;
        #pragma unroll
        for (int jj = 0; jj < 8; ++jj) s += ftanh(y[i][jj]) * w2r[jj];
        #pragma unroll
        for (int off = 1; off < 16; off <<= 1) s += __shfl_xor(s, off, 64);
        if (tx == 0) scores[row0 + ty + 16 * i] = s + b2s;
    }
}

// ---------------------------------------------------------------------------
// smax_k (shared by both paths)
// ---------------------------------------------------------------------------
__global__ __launch_bounds__(256) void smax_k(const float* __restrict__ scores,
                                              float* __restrict__ ml)
{
    __shared__ float red[256];
    const int b = blockIdx.x, tid = threadIdx.x;
    const float* sc = scores + (size_t)b * Sn;
    float m = -3.4e38f;
    for (int i = tid; i < Sn; i += 256) m = fmaxf(m, sc[i]);
    red[tid] = m;
    __syncthreads();
    for (int s = 128; s > 0; s >>= 1) {
        if (tid < s) red[tid] = fmaxf(red[tid], red[tid + s]);
        __syncthreads();
    }
    m = red[0];
    __syncthreads();
    float l = 0.f;
    for (int i = tid; i < Sn; i += 256) l += __expf(sc[i] - m);
    red[tid] = l;
    __syncthreads();
    for (int s = 128; s > 0; s >>= 1) {
        if (tid < s) red[tid] += red[tid + s];
        __syncthreads();
    }
    if (tid == 0) { ml[2 * b] = m; ml[2 * b + 1] = red[0]; }
}

// ---------------------------------------------------------------------------
// ctx_part_h: weighted sums, g fp16
// ---------------------------------------------------------------------------
__global__ __launch_bounds__(256) void ctx_part_h(
    const ushort_t* __restrict__ g, const float* __restrict__ scores,
    const float* __restrict__ ml, float* __restrict__ part)
{
    const int b = blockIdx.x >> 4, chunk = blockIdx.x & 15;
    const int tid = threadIdx.x, j = tid & 127, half = tid >> 7;
    const float m = ml[2 * b], linv = 1.0f / ml[2 * b + 1];
    const ushort_t* gp = g + ((size_t)b * Sn + chunk * 256) * Hn;
    const float* sp = scores + (size_t)b * Sn + chunk * 256;
    float acc = 0.f;
    for (int i = half; i < 256; i += 2) {
        float gv = (float)__builtin_bit_cast(_Float16, gp[(size_t)i * Hn + j]);
        acc = fmaf(__expf(sp[i] - m), gv, acc);
    }
    __shared__ float tmp[128];
    if (half) tmp[j] = acc;
    __syncthreads();
    if (!half) part[(size_t)blockIdx.x * Hn + j] = (acc + tmp[j]) * linv;
}

// ---------------------------------------------------------------------------
// ctx_final_k (shared)
// ---------------------------------------------------------------------------
__global__ __launch_bounds__(128) void ctx_final_k(const float* __restrict__ part,
                                                   float* __restrict__ out)
{
    const int b = blockIdx.x, j = threadIdx.x;
    float acc = 0.f;
    for (int c = 0; c < 16; ++c) acc += part[(size_t)(b * 16 + c) * Hn + j];
    out[b * Hn + j] = acc;
}

// ===========================================================================
// ====================== FALLBACK (round-8 proven) PATH =====================
// ===========================================================================
__global__ __launch_bounds__(256, 4) void gru_rec_fb(
    const float* __restrict__ x,
    const float* __restrict__ Wz, const float* __restrict__ bz,
    const float* __restrict__ Wr, const float* __restrict__ br,
    const float* __restrict__ Wh, const float* __restrict__ bh,
    float* __restrict__ gout)
{
    __shared__ __align__(16) _Float16 comb[192];
    __shared__ __align__(16) _Float16 comb2[192];

    const int b  = blockIdx.x & 31;
    const int p  = blockIdx.x >> 5;
    const int tw = p * CHUNK;
    const int t0 = (p == 0) ? 0 : tw - WARM;
    const int t1 = tw + CHUNK;

    const int k = threadIdx.x;
    const int j = k & 127;
    const bool zlane = (k < 128);
    const int base = (j >> 5) * 48;

    half2_t w2[24], wh2[24];
    const float* Wg = zlane ? Wz : Wr;
    #pragma unroll
    for (int c = 0; c < 24; ++c) {
        w2[c]  = (half2_t){(_Float16)Wg[j * 240 + 10 * c + 2],
                           (_Float16)Wg[j * 240 + 10 * c + 7]};
        wh2[c] = (half2_t){(_Float16)Wh[j * 240 + 10 * c + 2],
                           (_Float16)Wh[j * 240 + 10 * c + 7]};
    }
    const float bgate = zlane ? bz[j] : br[j];
    const float bhat  = bh[j];

    const float* xb = x + (size_t)b * Sn * Dn;
    float* gb = gout + (size_t)b * Sn * Hn;

    const bool stg = (k >= 128 && k < 160);
    const int  spar = (k >> 4) & 1;
    const int  sm = k & 15;

    if (stg && spar == 0) {
        float4 v = ((const float4*)(xb + (size_t)t0 * Dn))[sm];
        half4_t hv = {(_Float16)v.x, (_Float16)v.y, (_Float16)v.z, (_Float16)v.w};
        ((half4_t*)comb)[sm]  = hv;
        ((half4_t*)comb2)[sm] = hv;
    }
    if (k < 128) comb[64 + k] = (_Float16)0.f;

    float4 xs = make_float4(0.f, 0.f, 0.f, 0.f);
    if (stg && spar == 1)
        xs = ((const float4*)(xb + (size_t)(t0 + 1) * Dn))[sm];
    bar_lgkm();

    float gate = 0.f, hnew = 0.f;

    for (int t = t0; t < t1; ++t) {
        const float hj = zlane ? hnew : (float)comb[64 + j];
        if (stg && spar == (t & 1) && t + 2 < t1)
            xs = ((const float4*)(xb + (size_t)(t + 2) * Dn))[sm];
        if (k >= 248)
            ((half8_t*)comb2)[k - 248] = ((const half8_t*)comb)[k - 248];

        gate = fsig(windot<6>(comb + base, w2, bgate));
        if (!zlane) comb2[64 + j] = (_Float16)(gate * hj);
        else if (t > tw) gb[(size_t)(t - 1) * Hn + j] = hj;
        bar_lgkm();

        if (zlane) {
            const float hh = ftanh(windot<6>(comb2 + base, wh2, bhat));
            hnew = hj + gate * (hh - hj);
            comb[64 + j] = (_Float16)hnew;
        } else if (stg && spar == ((t + 1) & 1) && t + 1 < t1) {
            half4_t hv = {(_Float16)xs.x, (_Float16)xs.y,
                          (_Float16)xs.z, (_Float16)xs.w};
            ((half4_t*)comb)[sm] = hv;
        }
        bar_lgkm();
    }
    if (zlane) gb[(size_t)(t1 - 1) * Hn + j] = hnew;
}

__global__ __launch_bounds__(256, 2) void score_tile_fb(
    const float* __restrict__ g, const float* __restrict__ W1,
    const float* __restrict__ b1, const float* __restrict__ W2,
    const float* __restrict__ b2, float* __restrict__ scores)
{
    __shared__ __align__(16) ushort_t gph[128 * 136];
    __shared__ __align__(16) ushort_t w1p[128 * 136];

    const int tid = threadIdx.x;
    const int row0 = blockIdx.x * 128;
    const int tx = tid & 15, ty = tid >> 4;
    const int j0 = tx * 8;

    const float* gt = g + (size_t)row0 * 128;
    #pragma unroll
    for (int it = 0; it < 16; ++it) {
        const int idx = it * 1024 + tid * 4;
        const int rr = idx >> 7, cc = idx & 127;
        float4 v = *(const float4*)(gt + idx);
        ushort4v a = { f2bf(v.x), f2bf(v.y), f2bf(v.z), f2bf(v.w) };
        *(ushort4v*)(&gph[rr * 136 + cc]) = a;
        float4 u = *(const float4*)(W1 + idx);
        ushort4v c4 = { f2bf(u.x), f2bf(u.y), f2bf(u.z), f2bf(u.w) };
        *(ushort4v*)(&w1p[rr * 136 + cc]) = c4;
    }
    float b1r[8], w2r[8];
    #pragma unroll
    for (int i = 0; i < 8; ++i) { b1r[i] = b1[j0 + i]; w2r[i] = W2[j0 + i]; }
    const float b2s = b2[0];
    __syncthreads();

    float y[8][8];
    #pragma unroll
    for (int i = 0; i < 8; ++i)
        #pragma unroll
        for (int jj = 0; jj < 8; ++jj) y[i][jj] = b1r[jj];

    for (int k8 = 0; k8 < 16; ++k8) {
        const int kl = k8 * 8;
        ushort8v gf[8], wf[8];
        #pragma unroll
        for (int i = 0; i < 8; ++i)
            gf[i] = *(const ushort8v*)(&gph[(ty + 16 * i) * 136 + kl]);
        #pragma unroll
        for (int kk = 0; kk < 8; ++kk)
            wf[kk] = *(const ushort8v*)(&w1p[(kl + kk) * 136 + j0]);
        #pragma unroll
        for (int kk = 0; kk < 8; ++kk) {
            float wv[8];
            #pragma unroll
            for (int jj = 0; jj < 8; ++jj) wv[jj] = bf2f(wf[kk][jj]);
            #pragma unroll
            for (int i = 0; i < 8; ++i) {
                const float gv = bf2f(gf[i][kk]);
                #pragma unroll
                for (int jj = 0; jj < 8; ++jj)
                    y[i][jj] = fmaf(gv, wv[jj], y[i][jj]);
            }
        }
    }
    #pragma unroll
    for (int i = 0; i < 8; ++i) {
        float s = 0.f;
        #pragma unroll
        for (int jj = 0; jj < 8; ++jj) s += ftanh(y[i][jj]) * w2r[jj];
        #pragma unroll
        for (int off = 1; off < 16; off <<= 1) s += __shfl_xor(s, off, 64);
        if (tx == 0) scores[row0 + ty + 16 * i] = s + b2s;
    }
}

__global__ __launch_bounds__(256) void ctx_part_fb(
    const float* __restrict__ g, const float* __restrict__ scores,
    const float* __restrict__ ml, float* __restrict__ part)
{
    const int b = blockIdx.x >> 4, chunk = blockIdx.x & 15;
    const int tid = threadIdx.x, j = tid & 127, half = tid >> 7;
    const float m = ml[2 * b], linv = 1.0f / ml[2 * b + 1];
    const float* gp = g + ((size_t)b * Sn + chunk * 256) * Hn;
    const float* sp = scores + (size_t)b * Sn + chunk * 256;
    float acc = 0.f;
    for (int i = half; i < 256; i += 2)
        acc = fmaf(__expf(sp[i] - m), gp[(size_t)i * Hn + j], acc);
    __shared__ float tmp[128];
    if (half) tmp[j] = acc;
    __syncthreads();
    if (!half) part[(size_t)blockIdx.x * Hn + j] = (acc + tmp[j]) * linv;
}

// ===========================================================================
extern "C" void kernel_launch(void* const* d_in, const int* in_sizes, int n_in,
                              void* d_out, int out_size, void* d_ws, size_t ws_size,
                              hipStream_t stream)
{
    const float* x  = (const float*)d_in[0];
    const float* Wz = (const float*)d_in[1];
    const float* bz = (const float*)d_in[2];
    const float* Wr = (const float*)d_in[3];
    const float* br = (const float*)d_in[4];
    const float* Wh = (const float*)d_in[5];
    const float* bh = (const float*)d_in[6];
    const float* W1 = (const float*)d_in[7];
    const float* b1 = (const float*)d_in[8];
    const float* W2 = (const float*)d_in[9];
    const float* b2 = (const float*)d_in[10];
    float* out = (float*)d_out;
    char* ws = (char*)d_ws;

    // new-path layout: g16 32MB | pzh 33.55MB | prr 16.78MB | scores | ml | part
    const size_t OFF_PZH = 33554432;
    const size_t OFF_PRR = 67108864;
    const size_t OFF_SC  = 83886080;
    const size_t OFF_ML  = OFF_SC + 524288;
    const size_t OFF_PT  = OFF_ML + 256;
    const size_t NEED    = OFF_PT + 262144;   // 84,672,768

    if (ws_size >= NEED) {
        ushort_t* g16   = (ushort_t*)(ws);
        uint_t*   pzh   = (uint_t*)(ws + OFF_PZH);
        ushort_t* prr   = (ushort_t*)(ws + OFF_PRR);
        float* scores   = (float*)(ws + OFF_SC);
        float* ml       = (float*)(ws + OFF_ML);
        float* part     = (float*)(ws + OFF_PT);

        pre_k<<<1024, 256, 0, stream>>>(x, Wz, bz, Wr, br, Wh, bh, pzh, prr);
        gru_rec_p<<<32 * NCHUNK, 256, 0, stream>>>(pzh, prr, Wz, bz, Wr, br,
                                                   Wh, bh, g16);
        score_tile_h<<<1024, 256, 0, stream>>>(g16, W1, b1, W2, b2, scores);
        smax_k<<<32, 256, 0, stream>>>(scores, ml);
        ctx_part_h<<<512, 256, 0, stream>>>(g16, scores, ml, part);
        ctx_final_k<<<32, 128, 0, stream>>>(part, out);
    } else {
        // fallback: round-8 proven path (g fp32, 64.8 MB)
        float* g      = (float*)(ws);
        float* scores = (float*)(ws + 67108864);
        float* ml     = (float*)(ws + 67108864 + 524288);
        float* part   = (float*)(ws + 67108864 + 524288 + 256);

        gru_rec_fb<<<32 * NCHUNK, 256, 0, stream>>>(x, Wz, bz, Wr, br, Wh, bh, g);
        score_tile_fb<<<1024, 256, 0, stream>>>(g, W1, b1, W2, b2, scores);
        smax_k<<<32, 256, 0, stream>>>(scores, ml);
        ctx_part_fb<<<512, 256, 0, stream>>>(g, scores, ml, part);
        ctx_final_k<<<32, 128, 0, stream>>>(part, out);
    }
}

// Round 10
// 251.005 us; speedup vs baseline: 1.3159x; 1.3159x over previous
//
#include <hip/hip_runtime.h>

#define Bn 32
#define Sn 4096
#define Dn 64
#define Hn 128
#define CHUNK 128
#define WARM  32
#define NCHUNK (Sn / CHUNK)   // 32 -> 1024 blocks = 4 per CU

typedef unsigned short ushort_t;
typedef unsigned int uint_t;
typedef ushort_t ushort4v __attribute__((ext_vector_type(4)));
typedef ushort_t ushort8v __attribute__((ext_vector_type(8)));
typedef _Float16 half2_t __attribute__((ext_vector_type(2)));
typedef _Float16 half4_t __attribute__((ext_vector_type(4)));
typedef _Float16 half8_t __attribute__((ext_vector_type(8)));
typedef unsigned int uint2v __attribute__((ext_vector_type(2)));

__device__ __forceinline__ float fsig(float x)  { return 1.0f / (1.0f + __expf(-x)); }
__device__ __forceinline__ float ftanh(float x) { return 2.0f / (1.0f + __expf(-2.0f * x)) - 1.0f; }

__device__ __forceinline__ ushort_t f2bf(float f) {
    unsigned int b = __float_as_uint(f);
    b += 0x7fffu + ((b >> 16) & 1u);
    return (ushort_t)(b >> 16);
}
__device__ __forceinline__ float bf2f(ushort_t u) {
    return __uint_as_float(((unsigned int)u) << 16);
}

__device__ __forceinline__ void bar_lgkm() {
    asm volatile("s_waitcnt lgkmcnt(0)" ::: "memory");
    __builtin_amdgcn_s_barrier();
    asm volatile("" ::: "memory");
}

// NQ x half8 window read + NQ*4 fdot2, 4-way acc split, init carries bias/pre.
template<int NQ>
__device__ __forceinline__ float windot(const _Float16* p, const half2_t* w, float init) {
    float a0 = init, a1 = 0.f, a2 = 0.f, a3 = 0.f;
    const half8_t* cb = (const half8_t*)p;
    #pragma unroll
    for (int q = 0; q < NQ; ++q) {
        half8_t v = cb[q];
        a0 = __builtin_amdgcn_fdot2(w[4 * q + 0], (half2_t){v[0], v[1]}, a0, false);
        a1 = __builtin_amdgcn_fdot2(w[4 * q + 1], (half2_t){v[2], v[3]}, a1, false);
        a2 = __builtin_amdgcn_fdot2(w[4 * q + 2], (half2_t){v[4], v[5]}, a2, false);
        a3 = __builtin_amdgcn_fdot2(w[4 * q + 3], (half2_t){v[6], v[7]}, a3, false);
    }
    return (a0 + a1) + (a2 + a3);
}

// ===========================================================================
// ============================ precomp PATH =================================
// ===========================================================================

// ---------------------------------------------------------------------------
// wprep_k: pack the x-part center-tap weights into fp16 compact [192][64].
// o = j*3 + gate; row o has the 64-channel x-window weights of (j, gate)
// (zero outside the group's x slice). One-time cost, replaces 1024x scalar
// weight staging in pre_k (R9's tail pathology).
// ---------------------------------------------------------------------------
__global__ __launch_bounds__(256) void wprep_k(
    const float* __restrict__ Wz, const float* __restrict__ Wr,
    const float* __restrict__ Wh, _Float16* __restrict__ wx16)
{
    const int gid = blockIdx.x * 256 + threadIdx.x;
    if (gid >= 192 * 64) return;
    const int o = gid >> 6, c = gid & 63;
    const int j = o / 3, gate = o % 3;
    const float* Wg = (gate == 0) ? Wz : (gate == 1) ? Wr : Wh;
    float v = 0.f;
    if (j < 32) { if (c < 48) v = Wg[j * 240 + 5 * c + 2]; }
    else        { if (c >= 48) v = Wg[j * 240 + 5 * (c - 48) + 2]; }
    wx16[o * 64 + c] = (_Float16)v;
}

// ---------------------------------------------------------------------------
// pre_k: pre-activation GEMM over x for units j<64 (the only ones whose
// windows touch x). pzh[row][j] = half2(pre_z, pre_h); prr[row][j] = half.
// Grid: 1024 blocks x 256 thr; block = 128 rows; weights from wx16 (fp16,
// coalesced). o = j*3 + gate.
// ---------------------------------------------------------------------------
__global__ __launch_bounds__(256, 2) void pre_k(
    const float* __restrict__ x, const _Float16* __restrict__ wx16,
    const float* __restrict__ bz, const float* __restrict__ br,
    const float* __restrict__ bh,
    uint_t* __restrict__ pzh, ushort_t* __restrict__ prr)
{
    __shared__ __align__(16) _Float16 xt[128 * 72];    // [r][c] pad 72
    __shared__ __align__(16) _Float16 wfT[192 * 72];   // [o][c] pad 72

    const int tid = threadIdx.x;
    const int row0 = blockIdx.x * 128;

    // stage x tile (fp32 -> fp16), coalesced
    #pragma unroll
    for (int it = 0; it < 8; ++it) {
        const int idx = it * 1024 + tid * 4;
        const int r = idx >> 6, c = idx & 63;
        float4 v = *(const float4*)(x + (size_t)row0 * 64 + idx);
        half4_t hv = {(_Float16)v.x, (_Float16)v.y, (_Float16)v.z, (_Float16)v.w};
        *(half4_t*)(&xt[r * 72 + c]) = hv;
    }
    // stage packed weights (fp16, coalesced half8)
    #pragma unroll
    for (int it = 0; it < 6; ++it) {
        const int idx = it * 2048 + tid * 8;
        const int rr = idx >> 6, cc = idx & 63;
        half8_t v = *(const half8_t*)(wx16 + idx);
        *(half8_t*)(&wfT[rr * 72 + cc]) = v;
    }
    __syncthreads();

    const int tx = tid & 15, ty = tid >> 4;

    #pragma unroll
    for (int pass = 0; pass < 2; ++pass) {
        const int o0 = pass * 96 + tx * 6;
        float acc[8][6];
        #pragma unroll
        for (int o1 = 0; o1 < 6; ++o1) {
            const int o = o0 + o1, j = o / 3, gate = o % 3;
            const float bias = (gate == 0) ? bz[j] : (gate == 1) ? br[j] : bh[j];
            #pragma unroll
            for (int i = 0; i < 8; ++i) acc[i][o1] = bias;
        }
        for (int c8 = 0; c8 < 8; ++c8) {
            const int kl = c8 * 8;
            half8_t xv[8], wv[6];
            #pragma unroll
            for (int i = 0; i < 8; ++i)
                xv[i] = *(const half8_t*)(&xt[(ty + 16 * i) * 72 + kl]);
            #pragma unroll
            for (int o1 = 0; o1 < 6; ++o1)
                wv[o1] = *(const half8_t*)(&wfT[(o0 + o1) * 72 + kl]);
            #pragma unroll
            for (int o1 = 0; o1 < 6; ++o1)
                #pragma unroll
                for (int i = 0; i < 8; ++i) {
                    acc[i][o1] = __builtin_amdgcn_fdot2((half2_t){xv[i][0], xv[i][1]},
                                  (half2_t){wv[o1][0], wv[o1][1]}, acc[i][o1], false);
                    acc[i][o1] = __builtin_amdgcn_fdot2((half2_t){xv[i][2], xv[i][3]},
                                  (half2_t){wv[o1][2], wv[o1][3]}, acc[i][o1], false);
                    acc[i][o1] = __builtin_amdgcn_fdot2((half2_t){xv[i][4], xv[i][5]},
                                  (half2_t){wv[o1][4], wv[o1][5]}, acc[i][o1], false);
                    acc[i][o1] = __builtin_amdgcn_fdot2((half2_t){xv[i][6], xv[i][7]},
                                  (half2_t){wv[o1][6], wv[o1][7]}, acc[i][o1], false);
                }
        }
        const int u0 = o0 / 3;   // 2 units per thread per pass
        #pragma unroll
        for (int i = 0; i < 8; ++i) {
            const size_t row = row0 + ty + 16 * i;
            uint_t pz0 = __builtin_bit_cast(uint_t,
                (half2_t){(_Float16)acc[i][0], (_Float16)acc[i][2]});
            uint_t pz1 = __builtin_bit_cast(uint_t,
                (half2_t){(_Float16)acc[i][3], (_Float16)acc[i][5]});
            uint2v pp = {pz0, pz1};
            *(uint2v*)(&pzh[row * 64 + u0]) = pp;
            half2_t pr = {(_Float16)acc[i][1], (_Float16)acc[i][4]};
            *(uint_t*)(&prr[row * 64 + u0]) = __builtin_bit_cast(uint_t, pr);
        }
    }
}

// ---------------------------------------------------------------------------
// gru_rec_p: slim recurrence (round-9 proven, 195us). All x-dependence
// precomputed. comb = h (128 fp16), comb2 = r*h (128 fp16). 2 barriers/step.
// WARM=32: absmax bit-identical across WARM 96->64 => contraction ~0.67/step
// => 0.67^32 ~ 3e-6 added error.
// ---------------------------------------------------------------------------
__global__ __launch_bounds__(256, 4) void gru_rec_p(
    const uint_t* __restrict__ pzh, const ushort_t* __restrict__ prr,
    const float* __restrict__ Wz, const float* __restrict__ bz,
    const float* __restrict__ Wr, const float* __restrict__ br,
    const float* __restrict__ Wh, const float* __restrict__ bh,
    ushort_t* __restrict__ gout)
{
    __shared__ __align__(16) _Float16 comb[128];
    __shared__ __align__(16) _Float16 comb2[128];

    const int b  = blockIdx.x & 31;
    const int p  = blockIdx.x >> 5;
    const int tw = p * CHUNK;
    const int t0 = (p == 0) ? 0 : tw - WARM;
    const int t1 = tw + CHUNK;

    const int k = threadIdx.x;
    const int j = k & 127;
    const bool zlane = (k < 128);
    const bool lowj = (j < 64);
    const int hb = (j >= 96) ? 80 : 32;

    half2_t wg[24], whh[24];
    {
        const float* Wg = zlane ? Wz : Wr;
        if (j >= 64) {
            #pragma unroll
            for (int c = 0; c < 24; ++c) {
                wg[c]  = (half2_t){(_Float16)Wg[j * 240 + 10 * c + 2],
                                   (_Float16)Wg[j * 240 + 10 * c + 7]};
                whh[c] = (half2_t){(_Float16)Wh[j * 240 + 10 * c + 2],
                                   (_Float16)Wh[j * 240 + 10 * c + 7]};
            }
        } else if (j >= 32) {
            #pragma unroll
            for (int c = 0; c < 16; ++c) {
                wg[c]  = (half2_t){(_Float16)Wg[j * 240 + 10 * c + 82],
                                   (_Float16)Wg[j * 240 + 10 * c + 87]};
                whh[c] = (half2_t){(_Float16)Wh[j * 240 + 10 * c + 82],
                                   (_Float16)Wh[j * 240 + 10 * c + 87]};
            }
        } else {
            #pragma unroll
            for (int c = 0; c < 16; ++c) {
                wg[c] = (half2_t){(_Float16)0.f, (_Float16)0.f};
                whh[c] = (half2_t){(_Float16)0.f, (_Float16)0.f};
            }
        }
    }
    const float bg_hi = lowj ? 0.f : (zlane ? bz[j] : br[j]);
    const float bh_hi = lowj ? 0.f : bh[j];

    const uint_t*   pzb = pzh + (size_t)b * Sn * 64;
    const ushort_t* prb = prr + (size_t)b * Sn * 64;
    ushort_t* gb = gout + (size_t)b * Sn * Hn;

    comb[j] = (_Float16)0.f;

    uint_t  pz_next = 0; ushort_t pr_next = 0;
    if (zlane && lowj)  pz_next = pzb[(size_t)t0 * 64 + j];
    if (!zlane && lowj) pr_next = prb[(size_t)t0 * 64 + j];
    bar_lgkm();

    float z = 0.f, hreg = 0.f;
    half2_t pzv = (half2_t){(_Float16)0.f, (_Float16)0.f};

    for (int t = t0; t < t1; ++t) {
        // ---------------- phase A: gates ----------------
        const int tn = (t + 1 < Sn) ? (t + 1) : (Sn - 1);
        float preG;
        if (zlane) {
            pzv = __builtin_bit_cast(half2_t, pz_next);
            if (lowj) pz_next = pzb[(size_t)tn * 64 + j];
            preG = lowj ? (float)pzv[0] : bg_hi;
        } else {
            float prf = (float)__builtin_bit_cast(_Float16, pr_next);
            if (lowj) pr_next = prb[(size_t)tn * 64 + j];
            preG = lowj ? prf : bg_hi;
        }
        float hd = lowj ? windot<4>(comb, wg, preG)
                        : windot<6>(comb + hb, wg, preG);
        const float gate = fsig(hd);
        if (zlane) {
            z = gate;
        } else {
            const _Float16 hj16 = comb[j];
            comb2[j] = (_Float16)(gate * (float)hj16);
            if (t > tw)
                gb[(size_t)(t - 1) * Hn + j] = __builtin_bit_cast(ushort_t, hj16);
        }
        bar_lgkm();

        // ---------------- phase B: h_hat + update ----------------
        if (zlane) {
            const float preH = lowj ? (float)pzv[1] : bh_hi;
            float hdh = lowj ? windot<4>(comb2, whh, preH)
                             : windot<6>(comb2 + hb, whh, preH);
            const float hh = ftanh(hdh);
            hreg = hreg + z * (hh - hreg);
            comb[j] = (_Float16)hreg;
        }
        bar_lgkm();
    }
    if (zlane) {
        _Float16 hv = (_Float16)hreg;
        gb[(size_t)(t1 - 1) * Hn + j] = __builtin_bit_cast(ushort_t, hv);
    }
}

// ---------------------------------------------------------------------------
// score_ctx_h: scores = tanh(g.W1+b1).W2+b2 (fdot2 GEMM, g fp16 in LDS),
// then per-block flash partial: m_b, l_b = sum exp, ctx_b = sum p*g
// (g tile re-read from LDS — no extra HBM pass). Emits part[blk][132].
// ---------------------------------------------------------------------------
__global__ __launch_bounds__(256, 2) void score_ctx_h(
    const ushort_t* __restrict__ g, const float* __restrict__ W1,
    const float* __restrict__ b1, const float* __restrict__ W2,
    const float* __restrict__ b2, float* __restrict__ part)
{
    __shared__ __align__(16) _Float16 gph[128 * 136];   // [r][k]
    __shared__ __align__(16) _Float16 w1p[128 * 136];   // [k][j]
    __shared__ float sc[128];
    __shared__ float pl[128];
    __shared__ float red[8];
    __shared__ float tmp[128];

    const int tid = threadIdx.x;
    const int row0 = blockIdx.x * 128;
    const int tx = tid & 15, ty = tid >> 4;
    const int j0 = tx * 8;

    #pragma unroll
    for (int it = 0; it < 8; ++it) {           // g tile fp16 copy
        const int idx = it * 2048 + tid * 8;
        const int rr = idx >> 7, cc = idx & 127;
        half8_t v = *(const half8_t*)(g + (size_t)row0 * 128 + idx);
        *(half8_t*)(&gph[rr * 136 + cc]) = v;
    }
    #pragma unroll
    for (int it = 0; it < 16; ++it) {          // W1 fp32 -> fp16
        const int idx = it * 1024 + tid * 4;
        const int rr = idx >> 7, cc = idx & 127;
        float4 u = *(const float4*)(W1 + idx);
        half4_t hv = {(_Float16)u.x, (_Float16)u.y, (_Float16)u.z, (_Float16)u.w};
        *(half4_t*)(&w1p[rr * 136 + cc]) = hv;
    }

    float b1r[8], w2r[8];
    #pragma unroll
    for (int i = 0; i < 8; ++i) { b1r[i] = b1[j0 + i]; w2r[i] = W2[j0 + i]; }
    const float b2s = b2[0];
    __syncthreads();

    float y[8][8];
    #pragma unroll
    for (int i = 0; i < 8; ++i)
        #pragma unroll
        for (int jj = 0; jj < 8; ++jj) y[i][jj] = b1r[jj];

    for (int k8 = 0; k8 < 16; ++k8) {
        const int kl = k8 * 8;
        half8_t gf[8], wfk[8];
        #pragma unroll
        for (int i = 0; i < 8; ++i)
            gf[i] = *(const half8_t*)(&gph[(ty + 16 * i) * 136 + kl]);
        #pragma unroll
        for (int kk = 0; kk < 8; ++kk)
            wfk[kk] = *(const half8_t*)(&w1p[(kl + kk) * 136 + j0]);
        #pragma unroll
        for (int m = 0; m < 4; ++m) {
            half2_t wp[8];
            #pragma unroll
            for (int jj = 0; jj < 8; ++jj)
                wp[jj] = (half2_t){wfk[2 * m][jj], wfk[2 * m + 1][jj]};
            #pragma unroll
            for (int i = 0; i < 8; ++i) {
                half2_t gp = (half2_t){gf[i][2 * m], gf[i][2 * m + 1]};
                #pragma unroll
                for (int jj = 0; jj < 8; ++jj)
                    y[i][jj] = __builtin_amdgcn_fdot2(gp, wp[jj], y[i][jj], false);
            }
        }
    }

    #pragma unroll
    for (int i = 0; i < 8; ++i) {
        float s = 0.f;
        #pragma unroll
        for (int jj = 0; jj < 8; ++jj) s += ftanh(y[i][jj]) * w2r[jj];
        #pragma unroll
        for (int off = 1; off < 16; off <<= 1) s += __shfl_xor(s, off, 64);
        if (tx == 0) sc[ty + 16 * i] = s + b2s;
    }
    __syncthreads();

    // local softmax
    float mt = -3.4e38f;
    if (tid < 128) mt = sc[tid];
    #pragma unroll
    for (int off = 1; off < 64; off <<= 1) mt = fmaxf(mt, __shfl_xor(mt, off, 64));
    if ((tid & 63) == 0) red[tid >> 6] = mt;
    __syncthreads();
    const float m_b = fmaxf(red[0], red[1]);
    float pv = 0.f;
    if (tid < 128) { pv = __expf(sc[tid] - m_b); pl[tid] = pv; }
    #pragma unroll
    for (int off = 1; off < 64; off <<= 1) pv += __shfl_xor(pv, off, 64);
    if ((tid & 63) == 0) red[4 + (tid >> 6)] = pv;
    __syncthreads();
    const float l_b = red[4] + red[5];

    // ctx partial from the LDS g tile
    const int j = tid & 127, half = tid >> 7;
    float acc = 0.f;
    #pragma unroll 8
    for (int r = 0; r < 64; ++r)
        acc = fmaf(pl[half * 64 + r], (float)gph[(half * 64 + r) * 136 + j], acc);
    if (half) tmp[j] = acc;
    __syncthreads();
    if (!half) part[(size_t)blockIdx.x * 132 + j] = acc + tmp[j];
    if (tid == 0) {
        part[(size_t)blockIdx.x * 132 + 128] = m_b;
        part[(size_t)blockIdx.x * 132 + 129] = l_b;
    }
}

// ---------------------------------------------------------------------------
// merge_k: combine 32 segment partials per batch -> context (B, H)
// ---------------------------------------------------------------------------
__global__ __launch_bounds__(128) void merge_k(const float* __restrict__ part,
                                               float* __restrict__ out)
{
    const int b = blockIdx.x, j = threadIdx.x;
    const float* pp = part + (size_t)b * 32 * 132;
    float m = -3.4e38f;
    #pragma unroll
    for (int s = 0; s < 32; ++s) m = fmaxf(m, pp[s * 132 + 128]);
    float l = 0.f, cx = 0.f;
    #pragma unroll
    for (int s = 0; s < 32; ++s) {
        float e = __expf(pp[s * 132 + 128] - m);
        l  = fmaf(e, pp[s * 132 + 129], l);
        cx = fmaf(e, pp[s * 132 + j], cx);
    }
    out[b * Hn + j] = cx / l;
}

// ===========================================================================
// ====================== FALLBACK (round-8 proven) PATH =====================
// ===========================================================================
__global__ __launch_bounds__(256, 4) void gru_rec_fb(
    const float* __restrict__ x,
    const float* __restrict__ Wz, const float* __restrict__ bz,
    const float* __restrict__ Wr, const float* __restrict__ br,
    const float* __restrict__ Wh, const float* __restrict__ bh,
    float* __restrict__ gout)
{
    __shared__ __align__(16) _Float16 comb[192];
    __shared__ __align__(16) _Float16 comb2[192];

    const int b  = blockIdx.x & 31;
    const int p  = blockIdx.x >> 5;
    const int tw = p * CHUNK;
    const int t0 = (p == 0) ? 0 : tw - WARM;
    const int t1 = tw + CHUNK;

    const int k = threadIdx.x;
    const int j = k & 127;
    const bool zlane = (k < 128);
    const int base = (j >> 5) * 48;

    half2_t w2[24], wh2[24];
    const float* Wg = zlane ? Wz : Wr;
    #pragma unroll
    for (int c = 0; c < 24; ++c) {
        w2[c]  = (half2_t){(_Float16)Wg[j * 240 + 10 * c + 2],
                           (_Float16)Wg[j * 240 + 10 * c + 7]};
        wh2[c] = (half2_t){(_Float16)Wh[j * 240 + 10 * c + 2],
                           (_Float16)Wh[j * 240 + 10 * c + 7]};
    }
    const float bgate = zlane ? bz[j] : br[j];
    const float bhat  = bh[j];

    const float* xb = x + (size_t)b * Sn * Dn;
    float* gb = gout + (size_t)b * Sn * Hn;

    const bool stg = (k >= 128 && k < 160);
    const int  spar = (k >> 4) & 1;
    const int  sm = k & 15;

    if (stg && spar == 0) {
        float4 v = ((const float4*)(xb + (size_t)t0 * Dn))[sm];
        half4_t hv = {(_Float16)v.x, (_Float16)v.y, (_Float16)v.z, (_Float16)v.w};
        ((half4_t*)comb)[sm]  = hv;
        ((half4_t*)comb2)[sm] = hv;
    }
    if (k < 128) comb[64 + k] = (_Float16)0.f;

    float4 xs = make_float4(0.f, 0.f, 0.f, 0.f);
    if (stg && spar == 1)
        xs = ((const float4*)(xb + (size_t)(t0 + 1) * Dn))[sm];
    bar_lgkm();

    float gate = 0.f, hnew = 0.f;

    for (int t = t0; t < t1; ++t) {
        const float hj = zlane ? hnew : (float)comb[64 + j];
        if (stg && spar == (t & 1) && t + 2 < t1)
            xs = ((const float4*)(xb + (size_t)(t + 2) * Dn))[sm];
        if (k >= 248)
            ((half8_t*)comb2)[k - 248] = ((const half8_t*)comb)[k - 248];

        gate = fsig(windot<6>(comb + base, w2, bgate));
        if (!zlane) comb2[64 + j] = (_Float16)(gate * hj);
        else if (t > tw) gb[(size_t)(t - 1) * Hn + j] = hj;
        bar_lgkm();

        if (zlane) {
            const float hh = ftanh(windot<6>(comb2 + base, wh2, bhat));
            hnew = hj + gate * (hh - hj);
            comb[64 + j] = (_Float16)hnew;
        } else if (stg && spar == ((t + 1) & 1) && t + 1 < t1) {
            half4_t hv = {(_Float16)xs.x, (_Float16)xs.y,
                          (_Float16)xs.z, (_Float16)xs.w};
            ((half4_t*)comb)[sm] = hv;
        }
        bar_lgkm();
    }
    if (zlane) gb[(size_t)(t1 - 1) * Hn + j] = hnew;
}

__global__ __launch_bounds__(256, 2) void score_tile_fb(
    const float* __restrict__ g, const float* __restrict__ W1,
    const float* __restrict__ b1, const float* __restrict__ W2,
    const float* __restrict__ b2, float* __restrict__ scores)
{
    __shared__ __align__(16) ushort_t gph[128 * 136];
    __shared__ __align__(16) ushort_t w1p[128 * 136];

    const int tid = threadIdx.x;
    const int row0 = blockIdx.x * 128;
    const int tx = tid & 15, ty = tid >> 4;
    const int j0 = tx * 8;

    const float* gt = g + (size_t)row0 * 128;
    #pragma unroll
    for (int it = 0; it < 16; ++it) {
        const int idx = it * 1024 + tid * 4;
        const int rr = idx >> 7, cc = idx & 127;
        float4 v = *(const float4*)(gt + idx);
        ushort4v a = { f2bf(v.x), f2bf(v.y), f2bf(v.z), f2bf(v.w) };
        *(ushort4v*)(&gph[rr * 136 + cc]) = a;
        float4 u = *(const float4*)(W1 + idx);
        ushort4v c4 = { f2bf(u.x), f2bf(u.y), f2bf(u.z), f2bf(u.w) };
        *(ushort4v*)(&w1p[rr * 136 + cc]) = c4;
    }
    float b1r[8], w2r[8];
    #pragma unroll
    for (int i = 0; i < 8; ++i) { b1r[i] = b1[j0 + i]; w2r[i] = W2[j0 + i]; }
    const float b2s = b2[0];
    __syncthreads();

    float y[8][8];
    #pragma unroll
    for (int i = 0; i < 8; ++i)
        #pragma unroll
        for (int jj = 0; jj < 8; ++jj) y[i][jj] = b1r[jj];

    for (int k8 = 0; k8 < 16; ++k8) {
        const int kl = k8 * 8;
        ushort8v gf[8], wf[8];
        #pragma unroll
        for (int i = 0; i < 8; ++i)
            gf[i] = *(const ushort8v*)(&gph[(ty + 16 * i) * 136 + kl]);
        #pragma unroll
        for (int kk = 0; kk < 8; ++kk)
            wf[kk] = *(const ushort8v*)(&w1p[(kl + kk) * 136 + j0]);
        #pragma unroll
        for (int kk = 0; kk < 8; ++kk) {
            float wv[8];
            #pragma unroll
            for (int jj = 0; jj < 8; ++jj) wv[jj] = bf2f(wf[kk][jj]);
            #pragma unroll
            for (int i = 0; i < 8; ++i) {
                const float gv = bf2f(gf[i][kk]);
                #pragma unroll
                for (int jj = 0; jj < 8; ++jj)
                    y[i][jj] = fmaf(gv, wv[jj], y[i][jj]);
            }
        }
    }
    #pragma unroll
    for (int i = 0; i < 8; ++i) {
        float s = 0.f;
        #pragma unroll
        for (int jj = 0; jj < 8; ++jj) s += ftanh(y[i][jj]) * w2r[jj];
        #pragma unroll
        for (int off = 1; off < 16; off <<= 1) s += __shfl_xor(s, off, 64);
        if (tx == 0) scores[row0 + ty + 16 * i] = s + b2s;
    }
}

__global__ __launch_bounds__(256) void smax_k(const float* __restrict__ scores,
                                              float* __restrict__ ml)
{
    __shared__ float red[256];
    const int b = blockIdx.x, tid = threadIdx.x;
    const float* sc = scores + (size_t)b * Sn;
    float m = -3.4e38f;
    for (int i = tid; i < Sn; i += 256) m = fmaxf(m, sc[i]);
    red[tid] = m;
    __syncthreads();
    for (int s = 128; s > 0; s >>= 1) {
        if (tid < s) red[tid] = fmaxf(red[tid], red[tid + s]);
        __syncthreads();
    }
    m = red[0];
    __syncthreads();
    float l = 0.f;
    for (int i = tid; i < Sn; i += 256) l += __expf(sc[i] - m);
    red[tid] = l;
    __syncthreads();
    for (int s = 128; s > 0; s >>= 1) {
        if (tid < s) red[tid] += red[tid + s];
        __syncthreads();
    }
    if (tid == 0) { ml[2 * b] = m; ml[2 * b + 1] = red[0]; }
}

__global__ __launch_bounds__(256) void ctx_part_fb(
    const float* __restrict__ g, const float* __restrict__ scores,
    const float* __restrict__ ml, float* __restrict__ part)
{
    const int b = blockIdx.x >> 4, chunk = blockIdx.x & 15;
    const int tid = threadIdx.x, j = tid & 127, half = tid >> 7;
    const float m = ml[2 * b], linv = 1.0f / ml[2 * b + 1];
    const float* gp = g + ((size_t)b * Sn + chunk * 256) * Hn;
    const float* sp = scores + (size_t)b * Sn + chunk * 256;
    float acc = 0.f;
    for (int i = half; i < 256; i += 2)
        acc = fmaf(__expf(sp[i] - m), gp[(size_t)i * Hn + j], acc);
    __shared__ float tmp[128];
    if (half) tmp[j] = acc;
    __syncthreads();
    if (!half) part[(size_t)blockIdx.x * Hn + j] = (acc + tmp[j]) * linv;
}

__global__ __launch_bounds__(128) void ctx_final_fb(const float* __restrict__ part,
                                                    float* __restrict__ out)
{
    const int b = blockIdx.x, j = threadIdx.x;
    float acc = 0.f;
    for (int c = 0; c < 16; ++c) acc += part[(size_t)(b * 16 + c) * Hn + j];
    out[b * Hn + j] = acc;
}

// ===========================================================================
extern "C" void kernel_launch(void* const* d_in, const int* in_sizes, int n_in,
                              void* d_out, int out_size, void* d_ws, size_t ws_size,
                              hipStream_t stream)
{
    const float* x  = (const float*)d_in[0];
    const float* Wz = (const float*)d_in[1];
    const float* bz = (const float*)d_in[2];
    const float* Wr = (const float*)d_in[3];
    const float* br = (const float*)d_in[4];
    const float* Wh = (const float*)d_in[5];
    const float* bh = (const float*)d_in[6];
    const float* W1 = (const float*)d_in[7];
    const float* b1 = (const float*)d_in[8];
    const float* W2 = (const float*)d_in[9];
    const float* b2 = (const float*)d_in[10];
    float* out = (float*)d_out;
    char* ws = (char*)d_ws;

    // layout: g16 32MB | pzh 33.5MB | prr 16.8MB | wx16 24KB | part 528KB
    const size_t OFF_PZH  = 33554432;
    const size_t OFF_PRR  = 67108864;
    const size_t OFF_WX   = 83886080;
    const size_t OFF_PART = 83951616;
    const size_t NEED     = OFF_PART + 1024 * 132 * 4;   // 84,492,288

    if (ws_size >= NEED) {
        ushort_t* g16  = (ushort_t*)(ws);
        uint_t*   pzh  = (uint_t*)(ws + OFF_PZH);
        ushort_t* prr  = (ushort_t*)(ws + OFF_PRR);
        _Float16* wx16 = (_Float16*)(ws + OFF_WX);
        float*    part = (float*)(ws + OFF_PART);

        wprep_k<<<48, 256, 0, stream>>>(Wz, Wr, Wh, wx16);
        pre_k<<<1024, 256, 0, stream>>>(x, wx16, bz, br, bh, pzh, prr);
        gru_rec_p<<<32 * NCHUNK, 256, 0, stream>>>(pzh, prr, Wz, bz, Wr, br,
                                                   Wh, bh, g16);
        score_ctx_h<<<1024, 256, 0, stream>>>(g16, W1, b1, W2, b2, part);
        merge_k<<<32, 128, 0, stream>>>(part, out);
    } else {
        // fallback: round-8 proven path (g fp32, 64.8 MB)
        float* g      = (float*)(ws);
        float* scores = (float*)(ws + 67108864);
        float* ml     = (float*)(ws + 67108864 + 524288);
        float* part   = (float*)(ws + 67108864 + 524288 + 256);

        gru_rec_fb<<<32 * NCHUNK, 256, 0, stream>>>(x, Wz, bz, Wr, br, Wh, bh, g);
        score_tile_fb<<<1024, 256, 0, stream>>>(g, W1, b1, W2, b2, scores);
        smax_k<<<32, 256, 0, stream>>>(scores, ml);
        ctx_part_fb<<<512, 256, 0, stream>>>(g, scores, ml, part);
        ctx_final_fb<<<32, 128, 0, stream>>>(part, out);
    }
}